// Round 1
// baseline (329.743 us; speedup 1.0000x reference)
//
#include <hip/hip_runtime.h>

#define NN 4096
#define FF 256
#define HH 4
#define DD 64
#define NEG 0.2f

#define TI 16
#define JT 128
#define NSLICE 4
#define JRANGE (NN / NSLICE)

// ---------------- h = x @ W^T  (64x64 tile, 256 threads, 4x4 per thread) ----
__global__ __launch_bounds__(256) void gemm_h(const float* __restrict__ x,
                                              const float* __restrict__ W,
                                              float* __restrict__ h) {
    __shared__ __align__(16) float As[16][68];
    __shared__ __align__(16) float Bs[16][68];
    const int tid = threadIdx.x;
    const int m0 = blockIdx.x * 64, n0 = blockIdx.y * 64;
    const int lm = tid >> 2;          // 0..63 row of tile being loaded
    const int lk = (tid & 3) * 4;     // k quad
    const int tm0 = (tid >> 4) * 4;   // compute rows
    const int tn0 = (tid & 15) * 4;   // compute cols
    float acc[4][4] = {};
    const float* xp = x + (size_t)(m0 + lm) * FF + lk;
    const float* wp = W + (size_t)(n0 + lm) * FF + lk;
    for (int k0 = 0; k0 < FF; k0 += 16) {
        float4 av = *(const float4*)(xp + k0);
        float4 bv = *(const float4*)(wp + k0);
        As[lk + 0][lm] = av.x; As[lk + 1][lm] = av.y;
        As[lk + 2][lm] = av.z; As[lk + 3][lm] = av.w;
        Bs[lk + 0][lm] = bv.x; Bs[lk + 1][lm] = bv.y;
        Bs[lk + 2][lm] = bv.z; Bs[lk + 3][lm] = bv.w;
        __syncthreads();
#pragma unroll
        for (int k = 0; k < 16; k++) {
            float4 a = *(const float4*)&As[k][tm0];
            float4 b = *(const float4*)&Bs[k][tn0];
            float aa[4] = {a.x, a.y, a.z, a.w};
            float bb[4] = {b.x, b.y, b.z, b.w};
#pragma unroll
            for (int i = 0; i < 4; i++)
#pragma unroll
                for (int j = 0; j < 4; j++)
                    acc[i][j] = fmaf(aa[i], bb[j], acc[i][j]);
        }
        __syncthreads();
    }
#pragma unroll
    for (int i = 0; i < 4; i++) {
        float4 o = make_float4(acc[i][0], acc[i][1], acc[i][2], acc[i][3]);
        *(float4*)&h[(size_t)(m0 + tm0 + i) * FF + n0 + tn0] = o;
    }
}

// ---------------- s[n][h], t[n][h] ------------------------------------------
__global__ __launch_bounds__(256) void attn_st(const float* __restrict__ hfeat,
                                               const float* __restrict__ a_src,
                                               const float* __restrict__ a_dst,
                                               float* __restrict__ s,
                                               float* __restrict__ t) {
    const int n = blockIdx.x, tid = threadIdx.x;
    float v = hfeat[(size_t)n * FF + tid];
    float vs = v * a_src[tid];
    float vd = v * a_dst[tid];
#pragma unroll
    for (int off = 32; off > 0; off >>= 1) {
        vs += __shfl_down(vs, off, 64);
        vd += __shfl_down(vd, off, 64);
    }
    if ((tid & 63) == 0) {
        s[n * HH + (tid >> 6)] = vs;
        t[n * HH + (tid >> 6)] = vd;
    }
}

// ---------------- fused scores/softmax-numerator/PV --------------------------
// block: i-tile of 16 nodes x one j-slice of 1024; single pass over adj;
// unnormalized accumulation (shared upper-bound M makes partials additive).
__global__ __launch_bounds__(256) void gat_main(
    const float* __restrict__ adj, const float* __restrict__ hfeat,
    const float* __restrict__ s, const float* __restrict__ t,
    float* __restrict__ pden, float* __restrict__ out) {
    __shared__ __align__(16) float pw[HH][JT][TI];  // 32 KB
    __shared__ float sS[TI][HH];
    __shared__ float sM[TI][HH];
    __shared__ float gmax[HH];
    const int tid = threadIdx.x;
    const int i0 = blockIdx.x * TI;
    const int j0b = blockIdx.y * JRANGE;

    {   // global (unmasked) max of t per head — valid softmax shift upper bound
        float4* red = (float4*)&pw[0][0][0];
        float m0 = -3e38f, m1 = -3e38f, m2 = -3e38f, m3 = -3e38f;
        for (int n = tid; n < NN; n += 256) {
            float4 tv = *(const float4*)&t[(size_t)n * HH];
            m0 = fmaxf(m0, tv.x); m1 = fmaxf(m1, tv.y);
            m2 = fmaxf(m2, tv.z); m3 = fmaxf(m3, tv.w);
        }
        red[tid] = make_float4(m0, m1, m2, m3);
        __syncthreads();
        for (int off = 128; off > 0; off >>= 1) {
            if (tid < off) {
                float4 a = red[tid], b = red[tid + off];
                red[tid] = make_float4(fmaxf(a.x, b.x), fmaxf(a.y, b.y),
                                       fmaxf(a.z, b.z), fmaxf(a.w, b.w));
            }
            __syncthreads();
        }
        if (tid < HH) gmax[tid] = ((float*)red)[tid];
        __syncthreads();
    }
    if (tid < TI * HH) {
        int ii = tid >> 2, h = tid & 3;
        float sv = s[(size_t)(i0 + ii) * HH + h];
        sS[ii][h] = sv;
        float m = sv + gmax[h];
        sM[ii][h] = (m >= 0.f) ? m : NEG * m;   // lrelu monotone => bound
    }
    __syncthreads();

    const int ii_p = tid >> 4, sub = tid & 15;          // pw-phase mapping
    const int h_m = tid >> 6, dg = (tid >> 2) & 15, ig = tid & 3;  // mm mapping
    float dloc[HH] = {0.f, 0.f, 0.f, 0.f};
    float acc[4][4] = {};
    const float* hbase = hfeat + h_m * DD + dg * 4;
    float sSr[4], sMr[4];
#pragma unroll
    for (int h = 0; h < 4; h++) { sSr[h] = sS[ii_p][h]; sMr[h] = sM[ii_p][h]; }

    for (int jc = 0; jc < JRANGE; jc += JT) {
        const int j0 = j0b + jc;
        const float* arow = adj + (size_t)(i0 + ii_p) * NN + j0;
#pragma unroll
        for (int r = 0; r < JT / 16; r++) {
            int jj = sub + r * 16;
            float av = arow[jj];
            float4 tv = *(const float4*)&t[(size_t)(j0 + jj) * HH];
            float tvv[4] = {tv.x, tv.y, tv.z, tv.w};
            bool valid = (av > 0.f);
#pragma unroll
            for (int h = 0; h < 4; h++) {
                float e = 0.f;
                if (valid) {
                    float sc = sSr[h] + tvv[h];
                    sc = (sc >= 0.f) ? sc : NEG * sc;
                    e = __expf(sc - sMr[h]);
                    dloc[h] += e;
                }
                pw[h][jj][ii_p] = e * av;
            }
        }
        __syncthreads();
        const float* hj = hbase + (size_t)j0 * FF;
#pragma unroll 4
        for (int jj = 0; jj < JT; jj++) {
            float4 p = *(const float4*)&pw[h_m][jj][ig * 4];
            float4 hv = *(const float4*)(hj + (size_t)jj * FF);
            float pa[4] = {p.x, p.y, p.z, p.w};
            float hb[4] = {hv.x, hv.y, hv.z, hv.w};
#pragma unroll
            for (int a = 0; a < 4; a++)
#pragma unroll
                for (int b = 0; b < 4; b++)
                    acc[a][b] = fmaf(pa[a], hb[b], acc[a][b]);
        }
        __syncthreads();
    }

    {   // reduce per-thread denom partials (reuse pw as [TI][HH][16])
        float* dbuf = &pw[0][0][0];
#pragma unroll
        for (int h = 0; h < 4; h++) dbuf[(ii_p * 4 + h) * 16 + sub] = dloc[h];
        __syncthreads();
        if (tid < 64) {
            int ii = tid >> 2, h = tid & 3;
            float sum = 0.f;
#pragma unroll
            for (int k = 0; k < 16; k++) sum += dbuf[(ii * 4 + h) * 16 + k];
            atomicAdd(&pden[(size_t)(i0 + ii) * HH + h], sum);
        }
    }
#pragma unroll
    for (int a = 0; a < 4; a++) {
        float* orow = out + (size_t)(i0 + ig * 4 + a) * FF + h_m * DD + dg * 4;
#pragma unroll
        for (int b = 0; b < 4; b++) atomicAdd(orow + b, acc[a][b]);
    }
}

// ---------------- divide by denom; fully-masked rows -> 0 --------------------
__global__ __launch_bounds__(256) void finalize(float* __restrict__ out,
                                                const float* __restrict__ pden) {
    const int i = blockIdx.x, f = threadIdx.x;
    const int h = f >> 6;
    float d = pden[(size_t)i * HH + h];
    float v = out[(size_t)i * FF + f];
    out[(size_t)i * FF + f] = (d > 0.f) ? v / d : 0.f;
}

extern "C" void kernel_launch(void* const* d_in, const int* in_sizes, int n_in,
                              void* d_out, int out_size, void* d_ws, size_t ws_size,
                              hipStream_t stream) {
    const float* x     = (const float*)d_in[0];
    const float* adj   = (const float*)d_in[1];
    const float* W     = (const float*)d_in[2];
    const float* a_src = (const float*)d_in[3];
    const float* a_dst = (const float*)d_in[4];
    float* out = (float*)d_out;

    char* ws = (char*)d_ws;
    float* hfeat = (float*)ws;                                   // 4 MB
    float* s     = (float*)(ws + (size_t)NN * FF * 4);           // 64 KB
    float* t     = s + (size_t)NN * HH;                          // 64 KB
    float* pden  = t + (size_t)NN * HH;                          // 64 KB

    hipMemsetAsync(d_out, 0, (size_t)NN * FF * sizeof(float), stream);
    hipMemsetAsync(pden, 0, (size_t)NN * HH * sizeof(float), stream);

    gemm_h<<<dim3(NN / 64, FF / 64), 256, 0, stream>>>(x, W, hfeat);
    attn_st<<<NN, 256, 0, stream>>>(hfeat, a_src, a_dst, s, t);
    gat_main<<<dim3(NN / TI, NSLICE), 256, 0, stream>>>(adj, hfeat, s, t, pden, out);
    finalize<<<NN, 256, 0, stream>>>(out, pden);
}

// Round 2
// 180.175 us; speedup vs baseline: 1.8301x; 1.8301x over previous
//
#include <hip/hip_runtime.h>
#include <stdint.h>

#define NN 4096
#define FF 256
#define HH 4
#define DD 64
#define NEG 0.2f

#define ITILE 32
#define NSLICE 8
#define JRANGE (NN / NSLICE)   // 512
#define CJ 32

typedef __attribute__((ext_vector_type(8))) short short8;
typedef __attribute__((ext_vector_type(4))) float f32x4;
typedef __attribute__((ext_vector_type(16))) float f32x16;

__device__ __forceinline__ uint16_t bf16_rh(float f) {
    uint32_t u = __float_as_uint(f);
    return (uint16_t)((u + 0x8000u) >> 16);
}
__device__ __forceinline__ uint32_t enc_key(float f) {
    uint32_t u = __float_as_uint(f);
    return (u & 0x80000000u) ? ~u : (u | 0x80000000u);
}
__device__ __forceinline__ float dec_key(uint32_t k) {
    uint32_t u = (k & 0x80000000u) ? (k & 0x7fffffffu) : ~k;
    return __uint_as_float(u);
}

// ---------------- convert x, W to bf16 --------------------------------------
__global__ __launch_bounds__(256) void cvt_inputs(const float* __restrict__ x,
                                                  const float* __restrict__ W,
                                                  uint16_t* __restrict__ xb,
                                                  uint16_t* __restrict__ Wb) {
    const int idx = blockIdx.x * 256 + threadIdx.x;  // float4 index
    const int nx = NN * FF / 4;
    const int nw = FF * FF / 4;
    if (idx < nx) {
        float4 v = ((const float4*)x)[idx];
        ushort4 o;
        o.x = bf16_rh(v.x); o.y = bf16_rh(v.y);
        o.z = bf16_rh(v.z); o.w = bf16_rh(v.w);
        ((ushort4*)xb)[idx] = o;
    } else if (idx < nx + nw) {
        int k = idx - nx;
        float4 v = ((const float4*)W)[k];
        ushort4 o;
        o.x = bf16_rh(v.x); o.y = bf16_rh(v.y);
        o.z = bf16_rh(v.z); o.w = bf16_rh(v.w);
        ((ushort4*)Wb)[k] = o;
    }
}

// ---------------- h = x @ W^T via bf16 MFMA (fp32 acc/out) ------------------
// block: 64 i x 64 f, 4 waves i-split; frags loaded straight from global.
__global__ __launch_bounds__(256) void gemm_h(const uint16_t* __restrict__ xb,
                                              const uint16_t* __restrict__ Wb,
                                              float* __restrict__ h) {
    const int tid = threadIdx.x;
    const int w = tid >> 6, l = tid & 63;
    const int m = l & 15, q = l >> 4;             // 16x16x32: m=l&15, k=q*8+j
    const int i0 = blockIdx.x * 64 + w * 16;
    const int f0 = blockIdx.y * 64;
    f32x4 acc[4];
#pragma unroll
    for (int n = 0; n < 4; n++)
#pragma unroll
        for (int r = 0; r < 4; r++) acc[n][r] = 0.f;
    const uint16_t* arow = xb + (size_t)(i0 + m) * FF + q * 8;
#pragma unroll
    for (int k0 = 0; k0 < FF; k0 += 32) {
        short8 af = *(const short8*)(arow + k0);
#pragma unroll
        for (int n = 0; n < 4; n++) {
            short8 bf = *(const short8*)(Wb + (size_t)(f0 + n * 16 + m) * FF + k0 + q * 8);
            acc[n] = __builtin_amdgcn_mfma_f32_16x16x32_bf16(af, bf, acc[n], 0, 0, 0);
        }
    }
#pragma unroll
    for (int n = 0; n < 4; n++)
#pragma unroll
        for (int r = 0; r < 4; r++) {
            int row = q * 4 + r;                  // C: col=l&15, row=q*4+reg
            h[(size_t)(i0 + row) * FF + f0 + n * 16 + m] = acc[n][r];
        }
}

// ---------------- s,t + bf16 transpose H_T + global max key -----------------
// block: 64 nodes; thread (r,h) does the full 64-d dot for (node,head).
__global__ __launch_bounds__(256) void st_trans(const float* __restrict__ h,
                                                const float* __restrict__ a_src,
                                                const float* __restrict__ a_dst,
                                                float* __restrict__ s,
                                                float* __restrict__ T_T,
                                                uint16_t* __restrict__ H_T,
                                                uint32_t* __restrict__ gkey) {
    __shared__ uint16_t stage[64][258];
    const int tid = threadIdx.x;
    const int r = tid >> 2, hh = tid & 3;
    const int i0 = blockIdx.x * 64;
    const float* hrow = h + (size_t)(i0 + r) * FF + hh * DD;
    const float* as = a_src + hh * DD;
    const float* ad = a_dst + hh * DD;
    float vs = 0.f, vd = 0.f;
#pragma unroll
    for (int d4 = 0; d4 < DD; d4 += 4) {
        float4 hv = *(const float4*)(hrow + d4);
        float4 av = *(const float4*)(as + d4);
        float4 dv = *(const float4*)(ad + d4);
        vs += hv.x * av.x + hv.y * av.y + hv.z * av.z + hv.w * av.w;
        vd += hv.x * dv.x + hv.y * dv.y + hv.z * dv.z + hv.w * dv.w;
        uint32_t w0 = (uint32_t)bf16_rh(hv.x) | ((uint32_t)bf16_rh(hv.y) << 16);
        uint32_t w1 = (uint32_t)bf16_rh(hv.z) | ((uint32_t)bf16_rh(hv.w) << 16);
        *(uint32_t*)&stage[r][hh * DD + d4]     = w0;
        *(uint32_t*)&stage[r][hh * DD + d4 + 2] = w1;
    }
    s[(size_t)(i0 + r) * HH + hh] = vs;        // addr = i0*4 + tid: coalesced
    T_T[(size_t)hh * NN + i0 + r] = vd;
    float mx = vd;
#pragma unroll
    for (int off = 4; off < 64; off <<= 1) mx = fmaxf(mx, __shfl_down(mx, off, 64));
    if ((tid & 63) < 4) atomicMax(&gkey[tid & 3], enc_key(mx));
    __syncthreads();
    const int f = tid;                          // 0..255
#pragma unroll
    for (int c = 0; c < 64; c += 8) {
        union { uint16_t u[8]; short8 v; } o;
#pragma unroll
        for (int j = 0; j < 8; j++) o.u[j] = stage[c + j][f];
        *(short8*)(H_T + (size_t)f * NN + i0 + c) = o.v;
    }
}

// ---------------- fused scores -> exp -> P (A-frag regs) -> MFMA PV ---------
// block: 32 i x 512 j-slice; wave w = head w; adj staged via LDS (shared by
// all 4 heads); B-frags from L2-resident H_T; bf16 partials to ws.
__global__ __launch_bounds__(256) void gat_main(
    const float* __restrict__ adj, const uint16_t* __restrict__ H_T,
    const float* __restrict__ s, const float* __restrict__ T_T,
    const uint32_t* __restrict__ gkey, float* __restrict__ pden,
    uint16_t* __restrict__ part) {
    __shared__ float adj_s[CJ][ITILE + 1];      // transposed [j][i], 2-way-free
    const int tid = threadIdx.x;
    const int w = tid >> 6, l = tid & 63;
    const int m = l & 31, q = l >> 5;           // 32x32x16: m=l&31, k=q*8+j
    const int i0 = blockIdx.x * ITILE;
    const int sl = blockIdx.y;
    const int jb = sl * JRANGE;

    const float gm = dec_key(gkey[w]);
    const float sS = s[(size_t)(i0 + m) * HH + w];
    const float xM = sS + gm;
    const float ML = fmaxf(xM, NEG * xM);       // lrelu(s_i + max_j t_j) >= any valid score
    float den = 0.f;
    f32x16 acc0, acc1;
#pragma unroll
    for (int r = 0; r < 16; r++) { acc0[r] = 0.f; acc1[r] = 0.f; }
    const float* trow = T_T + (size_t)w * NN;
    const uint16_t* b0row = H_T + (size_t)(w * DD + m) * NN;
    const uint16_t* b1row = H_T + (size_t)(w * DD + 32 + m) * NN;

    for (int jc = jb; jc < jb + JRANGE; jc += CJ) {
        __syncthreads();
        {
            int is = tid >> 3, j4 = (tid & 7) * 4;
            float4 v = *(const float4*)(adj + (size_t)(i0 + is) * NN + jc + j4);
            adj_s[j4 + 0][is] = v.x; adj_s[j4 + 1][is] = v.y;
            adj_s[j4 + 2][is] = v.z; adj_s[j4 + 3][is] = v.w;
        }
        __syncthreads();
#pragma unroll
        for (int kk = 0; kk < CJ; kk += 16) {
            const int jg = jc + kk + q * 8;     // this lane's first j (global)
            float4 t0 = *(const float4*)(trow + jg);
            float4 t1 = *(const float4*)(trow + jg + 4);
            float tt[8] = {t0.x, t0.y, t0.z, t0.w, t1.x, t1.y, t1.z, t1.w};
            uint32_t pk[4];
#pragma unroll
            for (int jj = 0; jj < 8; jj += 2) {
                float av0 = adj_s[kk + q * 8 + jj][m];
                float av1 = adj_s[kk + q * 8 + jj + 1][m];
                float x0 = sS + tt[jj], x1 = sS + tt[jj + 1];
                float lr0 = fmaxf(x0, NEG * x0), lr1 = fmaxf(x1, NEG * x1);
                float e0 = __expf(lr0 - ML), e1 = __expf(lr1 - ML);
                e0 = (av0 > 0.f) ? e0 : 0.f;
                e1 = (av1 > 0.f) ? e1 : 0.f;
                den += e0 + e1;
                float p0 = e0 * av0, p1 = e1 * av1;
                uint32_t u0 = __float_as_uint(p0) + 0x8000u;
                uint32_t u1 = __float_as_uint(p1) + 0x8000u;
                pk[jj >> 1] = (u0 >> 16) | (u1 & 0xffff0000u);
            }
            union { uint32_t u[4]; short8 v; } afu;
#pragma unroll
            for (int c = 0; c < 4; c++) afu.u[c] = pk[c];
            short8 bf0 = *(const short8*)(b0row + jg);
            short8 bf1 = *(const short8*)(b1row + jg);
            acc0 = __builtin_amdgcn_mfma_f32_32x32x16_bf16(afu.v, bf0, acc0, 0, 0, 0);
            acc1 = __builtin_amdgcn_mfma_f32_32x32x16_bf16(afu.v, bf1, acc1, 0, 0, 0);
        }
    }
    den += __shfl_down(den, 32, 64);            // lanes l and l+32 share m
    if (l < 32) atomicAdd(&pden[(size_t)(i0 + m) * HH + w], den);
    uint16_t* pbase = part + (size_t)sl * NN * FF;
#pragma unroll
    for (int reg = 0; reg < 16; reg++) {
        int row = (reg & 3) + 8 * (reg >> 2) + 4 * q;  // C: col=l&31, verified m74
        pbase[(size_t)(i0 + row) * FF + w * DD + m]      = bf16_rh(acc0[reg]);
        pbase[(size_t)(i0 + row) * FF + w * DD + 32 + m] = bf16_rh(acc1[reg]);
    }
}

// ---------------- sum slice partials, divide by denom -----------------------
__global__ __launch_bounds__(256) void finalize(const uint16_t* __restrict__ part,
                                                const float* __restrict__ pden,
                                                float* __restrict__ out) {
    const int i = blockIdx.x, f = threadIdx.x;
    float sum = 0.f;
#pragma unroll
    for (int sl = 0; sl < NSLICE; sl++) {
        uint16_t v = part[(size_t)sl * NN * FF + (size_t)i * FF + f];
        sum += __uint_as_float(((uint32_t)v) << 16);
    }
    float d = pden[(size_t)i * HH + (f >> 6)];
    out[(size_t)i * FF + f] = (d > 0.f) ? sum / d : 0.f;
}

extern "C" void kernel_launch(void* const* d_in, const int* in_sizes, int n_in,
                              void* d_out, int out_size, void* d_ws, size_t ws_size,
                              hipStream_t stream) {
    const float* x     = (const float*)d_in[0];
    const float* adj   = (const float*)d_in[1];
    const float* W     = (const float*)d_in[2];
    const float* a_src = (const float*)d_in[3];
    const float* a_dst = (const float*)d_in[4];
    float* out = (float*)d_out;

    char* ws = (char*)d_ws;
    float*    h    = (float*)ws;                                   // 4 MB
    uint16_t* H_T  = (uint16_t*)(ws + (4u << 20));                 // 2 MB
    uint16_t* xb   = (uint16_t*)(ws + (6u << 20));                 // 2 MB
    uint16_t* Wb   = (uint16_t*)(ws + (8u << 20));                 // 128 KB
    float*    s    = (float*)(ws + (8u << 20) + (128u << 10));     // 64 KB
    float*    T_T  = s + (size_t)NN * HH;                          // 64 KB
    float*    pden = T_T + (size_t)HH * NN;                        // 64 KB
    uint32_t* gkey = (uint32_t*)(pden + (size_t)NN * HH);          // 16 B
    uint16_t* part = (uint16_t*)(ws + (9u << 20));                 // 16 MB

    hipMemsetAsync(pden, 0, (size_t)NN * HH * sizeof(float) + 32, stream);
    cvt_inputs<<<(NN * FF / 4 + FF * FF / 4 + 255) / 256, 256, 0, stream>>>(x, W, xb, Wb);
    gemm_h<<<dim3(NN / 64, FF / 64), 256, 0, stream>>>(xb, Wb, h);
    st_trans<<<NN / 64, 256, 0, stream>>>(h, a_src, a_dst, s, T_T, H_T, gkey);
    gat_main<<<dim3(NN / ITILE, NSLICE), 256, 0, stream>>>(adj, H_T, s, T_T, gkey, pden, part);
    finalize<<<NN, 256, 0, stream>>>(part, pden, out);
}